// Round 14
// baseline (550.479 us; speedup 1.0000x reference)
//
#include <hip/hip_runtime.h>
#include <math.h>

typedef _Float16 f16x8 __attribute__((ext_vector_type(8)));
typedef _Float16 f16x4 __attribute__((ext_vector_type(4)));
typedef float    f32x4 __attribute__((ext_vector_type(4)));

// XOR-swizzled index into a [rows][128] f16 LDS tile (256B rows, no pad).
__device__ __forceinline__ int swz(int row, int k)
{
    return row * 128 + (k ^ ((row & 15) << 3));
}

// ---------------- x f32 -> f16 (layer-1 gather input) ----------------
__global__ void xcvt(const float* __restrict__ x, _Float16* __restrict__ xf, int n8)
{
    int i = blockIdx.x * 256 + threadIdx.x;
    if (i >= n8) return;
    const float4* p = (const float4*)(x + (size_t)i * 8);
    float4 v0 = p[0], v1 = p[1];
    f16x8 o;
    o[0] = (_Float16)v0.x; o[1] = (_Float16)v0.y; o[2] = (_Float16)v0.z; o[3] = (_Float16)v0.w;
    o[4] = (_Float16)v1.x; o[5] = (_Float16)v1.y; o[6] = (_Float16)v1.z; o[7] = (_Float16)v1.w;
    *(f16x8*)&xf[(size_t)i * 8] = o;
}

// ---------------- W preprocess: fragment-major layout ----------------
__global__ void wsplit3(const float* __restrict__ W0, const float* __restrict__ W1,
                        const float* __restrict__ W2, _Float16* __restrict__ dst,
                        int M, int CHN)
{
    int total = 3 * CHN * 2 * 2 * 4 * 512;
    int idx = blockIdx.x * 256 + threadIdx.x;
    if (idx >= total) return;
    int e    = idx & 7;
    int lane = (idx >> 3) & 63;
    int kk   = (idx >> 9) & 3;
    int n    = (idx >> 11) & 1;
    int wc   = (idx >> 12) & 1;
    int rest = idx >> 13;
    int ch   = rest % CHN;
    int br   = rest / CHN;
    int col  = ch * 64 + wc * 32 + n * 16 + (lane & 15);
    int k    = kk * 32 + (lane >> 4) * 8 + e;
    const float* W = (br == 0) ? W0 : ((br == 1) ? W1 : W2);
    float v = (col < M) ? W[(size_t)k * M + col] : 0.f;
    _Float16 h = (_Float16)v;
    dst[idx] = h;
    dst[total + idx] = (_Float16)(v - (float)h);
}

// ---------------- MFMA helpers ----------------
__device__ __forceinline__ void mfma_x3(
    const _Float16* xh, const _Float16* xl,
    const _Float16* __restrict__ Wf, int plane, size_t fbase,
    int wc, int wr, int r, int g, int lane, f32x4 (&acc)[2][2])
{
    f16x8 Ah[2][4], Al[2][4];
    #pragma unroll
    for (int m = 0; m < 2; ++m)
        #pragma unroll
        for (int kk = 0; kk < 4; ++kk) {
            int o = swz(wr * 32 + m * 16 + r, kk * 32 + g * 8);
            Ah[m][kk] = *(const f16x8*)&xh[o];
            Al[m][kk] = *(const f16x8*)&xl[o];
        }
    #pragma unroll
    for (int n = 0; n < 2; ++n) {
        size_t fb = fbase + ((size_t)(wc * 2 + n) * 4) * 512 + lane * 8;
        #pragma unroll
        for (int kk = 0; kk < 4; ++kk) {
            f16x8 Bh = *(const f16x8*)&Wf[fb + kk * 512];
            f16x8 Bl = *(const f16x8*)&Wf[plane + fb + kk * 512];
            #pragma unroll
            for (int m = 0; m < 2; ++m) {
                acc[m][n] = __builtin_amdgcn_mfma_f32_16x16x32_f16(Ah[m][kk], Bh, acc[m][n], 0, 0, 0);
                acc[m][n] = __builtin_amdgcn_mfma_f32_16x16x32_f16(Ah[m][kk], Bl, acc[m][n], 0, 0, 0);
                acc[m][n] = __builtin_amdgcn_mfma_f32_16x16x32_f16(Al[m][kk], Bh, acc[m][n], 0, 0, 0);
            }
        }
    }
}

__device__ __forceinline__ void mfma_y2(
    const _Float16* yt,
    const _Float16* __restrict__ Wf, int plane, size_t fbase,
    int wc, int wr, int r, int g, int lane, f32x4 (&acc)[2][2])
{
    f16x8 Y[2][4];
    #pragma unroll
    for (int m = 0; m < 2; ++m)
        #pragma unroll
        for (int kk = 0; kk < 4; ++kk)
            Y[m][kk] = *(const f16x8*)&yt[swz(wr * 32 + m * 16 + r, kk * 32 + g * 8)];
    #pragma unroll
    for (int n = 0; n < 2; ++n) {
        size_t fb = fbase + ((size_t)(wc * 2 + n) * 4) * 512 + lane * 8;
        #pragma unroll
        for (int kk = 0; kk < 4; ++kk) {
            f16x8 Bh = *(const f16x8*)&Wf[fb + kk * 512];
            f16x8 Bl = *(const f16x8*)&Wf[plane + fb + kk * 512];
            #pragma unroll
            for (int m = 0; m < 2; ++m) {
                acc[m][n] = __builtin_amdgcn_mfma_f32_16x16x32_f16(Y[m][kk], Bh, acc[m][n], 0, 0, 0);
                acc[m][n] = __builtin_amdgcn_mfma_f32_16x16x32_f16(Y[m][kk], Bl, acc[m][n], 0, 0, 0);
            }
        }
    }
}

__device__ __forceinline__ void stage_f16(const _Float16* __restrict__ src, _Float16* dst,
                                          int row0, int nrows, int tid)
{
    #pragma unroll
    for (int i = 0; i < 4; ++i) {
        int idx = tid + i * 256;
        int row = idx >> 4;
        int kc  = (idx & 15) * 8;
        int gr  = row0 + row;
        f16x8 v = {};
        if (gr < nrows) v = *(const f16x8*)&src[(size_t)gr * 128 + kc];
        *(f16x8*)&dst[swz(row, kc)] = v;
    }
}

// ---------------- layer-1 GEMM: x f32 input, 48KB LDS, sequential y ----------------
__global__ __launch_bounds__(256)
void gemm3_f32(const float* __restrict__ X, const _Float16* __restrict__ y1,
               const _Float16* __restrict__ y2, const _Float16* __restrict__ Wf,
               const float* __restrict__ b0, const float* __restrict__ b1,
               const float* __restrict__ b2,
               _Float16* __restrict__ ohi, _Float16* __restrict__ olo, int nrows)
{
    __shared__ _Float16 xh[64 * 128], xl[64 * 128], yt[64 * 128];   // 48 KB
    const int tid = threadIdx.x, row0 = blockIdx.x * 64, ch = blockIdx.y;
    const int plane = 49152;

    #pragma unroll
    for (int i = 0; i < 8; ++i) {
        int idx = tid + i * 256;
        int row = idx >> 5;
        int k   = (idx & 31) * 4;
        int gr  = row0 + row;
        float4 v = (gr < nrows) ? *(const float4*)(X + (size_t)gr * 128 + k)
                                : make_float4(0.f, 0.f, 0.f, 0.f);
        float vv[4] = {v.x, v.y, v.z, v.w};
        f16x4 h, l;
        #pragma unroll
        for (int j = 0; j < 4; ++j) {
            _Float16 hj = (_Float16)vv[j];
            h[j] = hj; l[j] = (_Float16)(vv[j] - (float)hj);
        }
        int o = swz(row, k);
        *(f16x4*)&xh[o] = h; *(f16x4*)&xl[o] = l;
    }
    stage_f16(y1, yt, row0, nrows, tid);
    __syncthreads();

    const int lane = tid & 63, wid = tid >> 6;
    const int wr = wid >> 1, wc = wid & 1, r = lane & 15, g = lane >> 4;
    f32x4 acc[2][2] = {};
    mfma_x3(xh, xl, Wf, plane, (size_t)(0 * 2 + ch) * 8192, wc, wr, r, g, lane, acc);
    mfma_y2(yt, Wf, plane, (size_t)(1 * 2 + ch) * 8192, wc, wr, r, g, lane, acc);
    __syncthreads();
    stage_f16(y2, yt, row0, nrows, tid);
    __syncthreads();
    mfma_y2(yt, Wf, plane, (size_t)(2 * 2 + ch) * 8192, wc, wr, r, g, lane, acc);

    #pragma unroll
    for (int m = 0; m < 2; ++m)
        #pragma unroll
        for (int n = 0; n < 2; ++n) {
            int col = ch * 64 + wc * 32 + n * 16 + r;
            float bs = b0[col] + b1[col] + b2[col];
            #pragma unroll
            for (int i = 0; i < 4; ++i) {
                int row = row0 + wr * 32 + m * 16 + g * 4 + i;
                if (row < nrows) {
                    float v = acc[m][n][i] + bs;
                    _Float16 h = (_Float16)v;
                    ohi[(size_t)row * 128 + col] = h;
                    olo[(size_t)row * 128 + col] = (_Float16)(v - (float)h);
                }
            }
        }
}

// ---------------- layer-2 GEMM: hi/lo f16 input, 48KB LDS ----------------
__global__ __launch_bounds__(256)
void gemm3_f16(const _Float16* __restrict__ Xhi, const _Float16* __restrict__ Xlo,
               const _Float16* __restrict__ y1, const _Float16* __restrict__ y2,
               const _Float16* __restrict__ Wf,
               const float* __restrict__ b0, const float* __restrict__ b1,
               const float* __restrict__ b2,
               _Float16* __restrict__ ohi, _Float16* __restrict__ olo, int nrows)
{
    __shared__ _Float16 xh[64 * 128], xl[64 * 128], yt[64 * 128];
    const int tid = threadIdx.x, row0 = blockIdx.x * 64, ch = blockIdx.y;
    const int plane = 49152;

    stage_f16(Xhi, xh, row0, nrows, tid);
    stage_f16(Xlo, xl, row0, nrows, tid);
    stage_f16(y1, yt, row0, nrows, tid);
    __syncthreads();

    const int lane = tid & 63, wid = tid >> 6;
    const int wr = wid >> 1, wc = wid & 1, r = lane & 15, g = lane >> 4;
    f32x4 acc[2][2] = {};
    mfma_x3(xh, xl, Wf, plane, (size_t)(0 * 2 + ch) * 8192, wc, wr, r, g, lane, acc);
    mfma_y2(yt, Wf, plane, (size_t)(1 * 2 + ch) * 8192, wc, wr, r, g, lane, acc);
    __syncthreads();
    stage_f16(y2, yt, row0, nrows, tid);
    __syncthreads();
    mfma_y2(yt, Wf, plane, (size_t)(2 * 2 + ch) * 8192, wc, wr, r, g, lane, acc);

    #pragma unroll
    for (int m = 0; m < 2; ++m)
        #pragma unroll
        for (int n = 0; n < 2; ++n) {
            int col = ch * 64 + wc * 32 + n * 16 + r;
            float bs = b0[col] + b1[col] + b2[col];
            #pragma unroll
            for (int i = 0; i < 4; ++i) {
                int row = row0 + wr * 32 + m * 16 + g * 4 + i;
                if (row < nrows) {
                    float v = acc[m][n][i] + bs;
                    _Float16 h = (_Float16)v;
                    ohi[(size_t)row * 128 + col] = h;
                    olo[(size_t)row * 128 + col] = (_Float16)(v - (float)h);
                }
            }
        }
}

// ---------------- layer-3 GEMM (M=40) + fused log_softmax -> d_out ----------------
__global__ __launch_bounds__(256)
void gemm3_ls(const _Float16* __restrict__ Xhi, const _Float16* __restrict__ Xlo,
              const _Float16* __restrict__ y1, const _Float16* __restrict__ y2,
              const _Float16* __restrict__ Wf,
              const float* __restrict__ b0, const float* __restrict__ b1,
              const float* __restrict__ b2,
              float* __restrict__ out, int nrows)
{
    __shared__ _Float16 xh[64 * 128], xl[64 * 128], yt[64 * 128];
    const int tid = threadIdx.x, row0 = blockIdx.x * 64;
    const int plane = 24576;

    stage_f16(Xhi, xh, row0, nrows, tid);
    stage_f16(Xlo, xl, row0, nrows, tid);
    stage_f16(y1, yt, row0, nrows, tid);
    __syncthreads();

    const int lane = tid & 63, wid = tid >> 6;
    const int wr = wid >> 1, wc = wid & 1, r = lane & 15, g = lane >> 4;
    f32x4 acc[2][2] = {};
    mfma_x3(xh, xl, Wf, plane, (size_t)0 * 8192, wc, wr, r, g, lane, acc);
    mfma_y2(yt, Wf, plane, (size_t)1 * 8192, wc, wr, r, g, lane, acc);
    __syncthreads();
    stage_f16(y2, yt, row0, nrows, tid);
    __syncthreads();
    mfma_y2(yt, Wf, plane, (size_t)2 * 8192, wc, wr, r, g, lane, acc);

    __syncthreads();                       // xh dead; reuse as f32 [64][41] tile
    float* lst = (float*)xh;
    float bsv[2][2];
    #pragma unroll
    for (int m = 0; m < 2; ++m)
        #pragma unroll
        for (int n = 0; n < 2; ++n) {
            int col = wc * 32 + n * 16 + r;
            bsv[m][n] = (col < 40) ? (b0[col] + b1[col] + b2[col]) : 0.f;
            if (col < 40) {
                #pragma unroll
                for (int i = 0; i < 4; ++i) {
                    int row = wr * 32 + m * 16 + g * 4 + i;
                    lst[row * 41 + col] = acc[m][n][i] + bsv[m][n];
                }
            }
        }
    __syncthreads();
    __shared__ float lsr[64];
    if (tid < 64) {
        float mx = -INFINITY;
        for (int c = 0; c < 40; ++c) mx = fmaxf(mx, lst[tid * 41 + c]);
        float s = 0.f;
        for (int c = 0; c < 40; ++c) s += expf(lst[tid * 41 + c] - mx);
        lsr[tid] = mx + logf(s);
    }
    __syncthreads();
    #pragma unroll
    for (int m = 0; m < 2; ++m)
        #pragma unroll
        for (int n = 0; n < 2; ++n) {
            int col = wc * 32 + n * 16 + r;
            if (col >= 40) continue;
            #pragma unroll
            for (int i = 0; i < 4; ++i) {
                int lr  = wr * 32 + m * 16 + g * 4 + i;
                int row = row0 + lr;
                if (row < nrows)
                    out[(size_t)row * 40 + col] = acc[m][n][i] + bsv[m][n] - lsr[lr];
            }
        }
}

// ---------------- CSR build: packed dual-count histogram ----------------
__global__ void zero_i32(int* __restrict__ p, int n)
{
    int i = blockIdx.x * 256 + threadIdx.x;
    if (i < n) p[i] = 0;
}

__global__ void hist_p(const int* __restrict__ ei1, const int* __restrict__ ei2,
                       int E, int* __restrict__ cnt)
{
    int i = blockIdx.x * 256 + threadIdx.x;
    if (i >= 2 * E) return;
    if (i < E) atomicAdd(&cnt[ei1[E + i]], 1);
    else       atomicAdd(&cnt[ei2[E + (i - E)]], 0x10000);
}

__device__ __forceinline__ int pcnt(int c) { return (c & 0xffff) + ((unsigned)c >> 16); }

__global__ void scan_phase1(const int* __restrict__ cnt, int ncnt, int* __restrict__ bsums, int n)
{
    __shared__ int s[256];
    int tid = threadIdx.x;
    int i = blockIdx.x * 256 + tid;
    int v = (i < n && i < ncnt) ? pcnt(cnt[i]) : 0;
    s[tid] = v; __syncthreads();
    for (int off = 128; off; off >>= 1) {
        if (tid < off) s[tid] += s[tid + off];
        __syncthreads();
    }
    if (tid == 0) bsums[blockIdx.x] = s[0];
}

__global__ void scan_phase2(int* __restrict__ bsums, int nb)
{
    __shared__ int s[256];
    int tid = threadIdx.x;
    int v = (tid < nb) ? bsums[tid] : 0;
    s[tid] = v; __syncthreads();
    for (int off = 1; off < 256; off <<= 1) {
        int t = (tid >= off) ? s[tid - off] : 0;
        __syncthreads();
        s[tid] += t;
        __syncthreads();
    }
    if (tid < nb) bsums[tid] = s[tid] - v;   // exclusive
}

__global__ void scan_phase3(const int* __restrict__ cnt, int ncnt,
                            const int* __restrict__ bsums, int* __restrict__ row_ptr, int n)
{
    __shared__ int s[256];
    int tid = threadIdx.x;
    int i = blockIdx.x * 256 + tid;
    int v = (i < n && i < ncnt) ? pcnt(cnt[i]) : 0;
    s[tid] = v; __syncthreads();
    for (int off = 1; off < 256; off <<= 1) {
        int t = (tid >= off) ? s[tid - off] : 0;
        __syncthreads();
        s[tid] += t;
        __syncthreads();
    }
    if (i < n) row_ptr[i] = s[tid] - v + bsums[blockIdx.x];
}

__global__ void mk_mid(const int* __restrict__ rp, int* __restrict__ cnt,
                       int* __restrict__ c1, int* __restrict__ mid, int N)
{
    int i = blockIdx.x * 256 + threadIdx.x;
    if (i < N) { mid[i] = rp[i] + (cnt[i] & 0xffff); cnt[i] = 0; c1[i] = 0; }
}

__global__ void init_bincur(const int* __restrict__ rp, int N, int nbins, int* __restrict__ bincur)
{
    int b = blockIdx.x * 256 + threadIdx.x;
    if (b < nbins) {
        int r = b << 9;
        bincur[b] = rp[r < N ? r : N];
    }
}

constexpr int EPB  = 2048;
constexpr int MAXB = 128;

__global__ __launch_bounds__(256)
void binfill(const int* __restrict__ ei1, const float* __restrict__ ew1,
             const int* __restrict__ ei2, const float* __restrict__ ew2,
             int E, int N, int nbins, int* __restrict__ bincur,
             long long* __restrict__ stage, unsigned short* __restrict__ soff)
{
    __shared__ int hist[MAXB];
    __shared__ int scanb[MAXB];
    __shared__ int gbase[MAXB];
    __shared__ long long srec[EPB];
    __shared__ unsigned short sdo[EPB];
    __shared__ unsigned char  sbin[EPB];

    const int t = threadIdx.x;
    const long long base = (long long)blockIdx.x * EPB;
    int total = 2 * E - (int)base; if (total > EPB) total = EPB;

    for (int i = t; i < MAXB; i += 256) hist[i] = 0;
    __syncthreads();

    int myb[8], myr[8], myo[8];
    long long myrec[8];
    #pragma unroll
    for (int k = 0; k < 8; ++k) {
        int i = t + k * 256;
        myb[k] = -1;
        if (i < total) {
            int j = (int)(base + i);
            int set = (j >= E);
            int e = set ? j - E : j;
            const int* ei = set ? ei2 : ei1;
            int d = ei[E + e];
            int s = ei[e] + (set ? N : 0);      // set bit encoded as +N
            float w = set ? ew2[e] : ew1[e];
            myb[k] = d >> 9;
            myo[k] = d & 511;
            myrec[k] = ((long long)__float_as_int(w) << 32) | (unsigned)s;
            myr[k] = atomicAdd(&hist[myb[k]], 1);
        }
    }
    __syncthreads();

    if (t < MAXB) scanb[t] = hist[t];
    __syncthreads();
    for (int off = 1; off < MAXB; off <<= 1) {
        int tv = 0;
        if (t < MAXB && t >= off) tv = scanb[t - off];
        __syncthreads();
        if (t < MAXB) scanb[t] += tv;
        __syncthreads();
    }
    if (t < nbins && hist[t] > 0)
        gbase[t] = atomicAdd(&bincur[t], hist[t]);
    __syncthreads();

    #pragma unroll
    for (int k = 0; k < 8; ++k) {
        if (myb[k] >= 0) {
            int slot = scanb[myb[k]] - hist[myb[k]] + myr[k];
            srec[slot] = myrec[k];
            sdo[slot]  = (unsigned short)myo[k];
            sbin[slot] = (unsigned char)myb[k];
        }
    }
    __syncthreads();

    #pragma unroll
    for (int k = 0; k < 8; ++k) {
        int i = t + k * 256;
        if (i < total) {
            int b = sbin[i];
            int addr = gbase[b] + (i - (scanb[b] - hist[b]));
            stage[addr] = srec[i];
            soff[addr]  = sdo[i];
        }
    }
}

__global__ __launch_bounds__(256)
void binplace(const long long* __restrict__ stage, const unsigned short* __restrict__ soff,
              const int* __restrict__ rp, const int* __restrict__ mid, int N,
              int* __restrict__ cur1, int* __restrict__ cur2,
              long long* __restrict__ pack)
{
    int bin  = blockIdx.x >> 1;
    int half = blockIdx.x & 1;
    int r0 = bin << 9;
    int r1 = r0 + 512; if (r1 > N) r1 = N;
    if (r0 >= N) return;
    int beg = rp[r0], end = rp[r1];
    int md = beg + ((end - beg + 1) >> 1);
    int lo = half ? md : beg;
    int hi = half ? end : md;
    for (int i = lo + threadIdx.x; i < hi; i += 256) {
        long long rec = stage[i];
        unsigned sp = (unsigned)rec;
        int d = r0 + soff[i];
        int set = sp >= (unsigned)N;
        unsigned s = set ? sp - N : sp;
        int p = set ? mid[d] + atomicAdd(&cur2[d], 1)
                    : rp[d]  + atomicAdd(&cur1[d], 1);
        pack[p] = (rec & 0xffffffff00000000LL) | s;
    }
}

// ---------------- XCD-sliced dual gather: slice = blockIdx.x & 3 ----------------
// Each XCD (id%8 = slice or slice+4) touches only cols [slice*32, slice*32+32)
// of xf -> 3.2 MB working set, fits 4 MB per-XCD L2; 24x row reuse becomes L2 hits.
__global__ __launch_bounds__(256)
void gather_ys(const _Float16* __restrict__ xf, const int* __restrict__ rp,
               const int* __restrict__ mid, const long long* __restrict__ pack,
               _Float16* __restrict__ y1, _Float16* __restrict__ y2, int N)
{
    int bid   = blockIdx.x;
    int slice = bid & 3;
    int row   = (bid >> 2) * 64 + (threadIdx.x >> 2);
    if (row >= N) return;
    int lane = threadIdx.x & 3;                 // 4 lanes per row
    int cb   = slice * 32 + lane * 8;           // 8 f16 per lane
    int b = rp[row], md = mid[row], e = rp[row + 1];
    float a[8] = {}, c[8] = {};
    int i = b;
    for (; i + 2 <= md; i += 2) {
        long long q0 = __builtin_nontemporal_load(&pack[i]);
        long long q1 = __builtin_nontemporal_load(&pack[i + 1]);
        f16x8 v0 = *(const f16x8*)(xf + (size_t)(unsigned)q0 * 128 + cb);
        f16x8 v1 = *(const f16x8*)(xf + (size_t)(unsigned)q1 * 128 + cb);
        float w0 = __int_as_float((int)(q0 >> 32));
        float w1 = __int_as_float((int)(q1 >> 32));
        #pragma unroll
        for (int j = 0; j < 8; ++j) {
            a[j] = fmaf(w0, (float)v0[j], a[j]);
            a[j] = fmaf(w1, (float)v1[j], a[j]);
        }
    }
    if (i < md) {
        long long q0 = __builtin_nontemporal_load(&pack[i]);
        f16x8 v0 = *(const f16x8*)(xf + (size_t)(unsigned)q0 * 128 + cb);
        float w0 = __int_as_float((int)(q0 >> 32));
        #pragma unroll
        for (int j = 0; j < 8; ++j) a[j] = fmaf(w0, (float)v0[j], a[j]);
    }
    i = md;
    for (; i + 2 <= e; i += 2) {
        long long q0 = __builtin_nontemporal_load(&pack[i]);
        long long q1 = __builtin_nontemporal_load(&pack[i + 1]);
        f16x8 v0 = *(const f16x8*)(xf + (size_t)(unsigned)q0 * 128 + cb);
        f16x8 v1 = *(const f16x8*)(xf + (size_t)(unsigned)q1 * 128 + cb);
        float w0 = __int_as_float((int)(q0 >> 32));
        float w1 = __int_as_float((int)(q1 >> 32));
        #pragma unroll
        for (int j = 0; j < 8; ++j) {
            c[j] = fmaf(w0, (float)v0[j], c[j]);
            c[j] = fmaf(w1, (float)v1[j], c[j]);
        }
    }
    if (i < e) {
        long long q0 = __builtin_nontemporal_load(&pack[i]);
        f16x8 v0 = *(const f16x8*)(xf + (size_t)(unsigned)q0 * 128 + cb);
        float w0 = __int_as_float((int)(q0 >> 32));
        #pragma unroll
        for (int j = 0; j < 8; ++j) c[j] = fmaf(w0, (float)v0[j], c[j]);
    }
    f16x8 o1, o2;
    #pragma unroll
    for (int j = 0; j < 8; ++j) { o1[j] = (_Float16)a[j]; o2[j] = (_Float16)c[j]; }
    *(f16x8*)&y1[(size_t)row * 128 + cb] = o1;
    *(f16x8*)&y2[(size_t)row * 128 + cb] = o2;
}

// ---------------- launch ----------------
extern "C" void kernel_launch(void* const* d_in, const int* in_sizes, int n_in,
                              void* d_out, int out_size, void* d_ws, size_t ws_size,
                              hipStream_t stream)
{
    const float* x    = (const float*)d_in[0];
    const int*   ei1  = (const int*)  d_in[1];
    const float* ew1  = (const float*)d_in[2];
    const int*   ei2  = (const int*)  d_in[3];
    const float* ew2  = (const float*)d_in[4];

    const float* W_ln1 = (const float*)d_in[5];   const float* b_ln1 = (const float*)d_in[6];
    const float* W_c11 = (const float*)d_in[7];   const float* b_c11 = (const float*)d_in[8];
    const float* W_c21 = (const float*)d_in[9];   const float* b_c21 = (const float*)d_in[10];
    const float* W_ln2 = (const float*)d_in[11];  const float* b_ln2 = (const float*)d_in[12];
    const float* W_c12 = (const float*)d_in[13];  const float* b_c12 = (const float*)d_in[14];
    const float* W_c22 = (const float*)d_in[15];  const float* b_c22 = (const float*)d_in[16];
    const float* W_ln3 = (const float*)d_in[17];  const float* b_ln3 = (const float*)d_in[18];
    const float* W_c13 = (const float*)d_in[19];  const float* b_c13 = (const float*)d_in[20];
    const float* W_c23 = (const float*)d_in[21];  const float* b_c23 = (const float*)d_in[22];

    const int N = in_sizes[0] / 128;   // 50000
    const int E = in_sizes[2];         // 600000
    const int nbins = (N + 511) >> 9;  // 98

    // ---- workspace layout ----
    auto align_up = [](size_t v) { return (v + 255) & ~(size_t)255; };
    char* base = (char*)d_ws;
    size_t off = 0;
    auto take = [&](size_t bytes) { char* p = base + off; off += align_up(bytes); return p; };

    _Float16* xf0  = (_Float16*)take((size_t)N * 128 * 2);
    _Float16* xAh  = (_Float16*)take((size_t)N * 128 * 2);
    _Float16* xAl  = (_Float16*)take((size_t)N * 128 * 2);
    _Float16* xBh  = (_Float16*)take((size_t)N * 128 * 2);
    _Float16* xBl  = (_Float16*)take((size_t)N * 128 * 2);
    _Float16* y1   = (_Float16*)take((size_t)N * 128 * 2);
    _Float16* y2   = (_Float16*)take((size_t)N * 128 * 2);

    _Float16* Wt1 = (_Float16*)take((size_t)2 * 49152 * 2);
    _Float16* Wt2 = (_Float16*)take((size_t)2 * 49152 * 2);
    _Float16* Wt3 = (_Float16*)take((size_t)2 * 24576 * 2);

    int*       cnt  = (int*)      take((size_t)N * 4);
    int*       c1   = (int*)      take((size_t)N * 4);
    int*       mid  = (int*)      take((size_t)N * 4);
    int*       rp   = (int*)      take((size_t)(N + 1) * 4);
    long long* pack = (long long*)take((size_t)2 * E * 8);
    int*       bs   = (int*)      take(256 * 4);
    int*       bincur = (int*)    take(MAXB * 4);

    // CSR staging aliases y1/y2 (dead until first gather_ys)
    long long*      stage = (long long*)y1;
    unsigned short* soff  = (unsigned short*)y2;

    dim3 blk(256);
    const int gN   = (N + 255) / 256;
    const int gN1  = (N + 1 + 255) / 256;
    const int gE2  = (2 * E + 255) / 256;
    const int gBF  = (2 * E + EPB - 1) / EPB;
    const int gRT  = (N + 63) / 64;
    dim3 gg128(gRT, 2);
    dim3 gg40(gRT, 1);
    dim3 ggs(4 * gRT);                   // 4 col-slices x row-blocks
    const int n8 = N * 128 / 8;

    // ---- preprocessing ----
    xcvt<<<(n8 + 255) / 256, blk, 0, stream>>>(x, xf0, n8);
    wsplit3<<<(49152 + 255) / 256, blk, 0, stream>>>(W_ln1, W_c11, W_c21, Wt1, 128, 2);
    wsplit3<<<(49152 + 255) / 256, blk, 0, stream>>>(W_ln2, W_c12, W_c22, Wt2, 128, 2);
    wsplit3<<<(24576 + 255) / 256, blk, 0, stream>>>(W_ln3, W_c13, W_c23, Wt3, 40, 1);

    // ---- build combined CSR (packed dual-count histogram) ----
    zero_i32<<<gN, blk, 0, stream>>>(cnt, N);
    hist_p<<<gE2, blk, 0, stream>>>(ei1, ei2, E, cnt);
    scan_phase1<<<gN1, blk, 0, stream>>>(cnt, N, bs, N + 1);
    scan_phase2<<<1, blk, 0, stream>>>(bs, gN1);
    scan_phase3<<<gN1, blk, 0, stream>>>(cnt, N, bs, rp, N + 1);
    mk_mid<<<gN, blk, 0, stream>>>(rp, cnt, c1, mid, N);
    init_bincur<<<1, blk, 0, stream>>>(rp, N, nbins, bincur);
    binfill<<<gBF, blk, 0, stream>>>(ei1, ew1, ei2, ew2, E, N, nbins, bincur, stage, soff);
    binplace<<<nbins * 2, blk, 0, stream>>>(stage, soff, rp, mid, N, cnt, c1, pack);

    // ---- layer 1 ----
    gather_ys<<<ggs, blk, 0, stream>>>(xf0, rp, mid, pack, y1, y2, N);
    gemm3_f32<<<gg128, blk, 0, stream>>>(x, y1, y2, Wt1, b_ln1, b_c11, b_c21, xAh, xAl, N);

    // ---- layer 2 ----
    gather_ys<<<ggs, blk, 0, stream>>>(xAh, rp, mid, pack, y1, y2, N);
    gemm3_f16<<<gg128, blk, 0, stream>>>(xAh, xAl, y1, y2, Wt2, b_ln2, b_c12, b_c22, xBh, xBl, N);

    // ---- layer 3 + fused log_softmax ----
    gather_ys<<<ggs, blk, 0, stream>>>(xBh, rp, mid, pack, y1, y2, N);
    gemm3_ls<<<gg40, blk, 0, stream>>>(xBh, xBl, y1, y2, Wt3, b_ln3, b_c13, b_c23, (float*)d_out, N);
}

// Round 15
// 349.977 us; speedup vs baseline: 1.5729x; 1.5729x over previous
//
#include <hip/hip_runtime.h>
#include <math.h>

typedef _Float16 f16x8 __attribute__((ext_vector_type(8)));
typedef _Float16 f16x4 __attribute__((ext_vector_type(4)));
typedef float    f32x4 __attribute__((ext_vector_type(4)));

// XOR-swizzled index into a [rows][128] f16 LDS tile (256B rows, no pad).
__device__ __forceinline__ int swz(int row, int k)
{
    return row * 128 + (k ^ ((row & 15) << 3));
}

// ---------------- W preprocess: fragment-major layout ----------------
// For each (br, ch, wc, n, kk): one 512-f16 fragment; lane l holds elems for
// col = ch*64 + wc*32 + n*16 + (l&15), k = kk*32 + (l>>4)*8 + e.
__global__ void wsplit3(const float* __restrict__ W0, const float* __restrict__ W1,
                        const float* __restrict__ W2, _Float16* __restrict__ dst,
                        int M, int CHN)
{
    int total = 3 * CHN * 2 * 2 * 4 * 512;
    int idx = blockIdx.x * 256 + threadIdx.x;
    if (idx >= total) return;
    int e    = idx & 7;
    int lane = (idx >> 3) & 63;
    int kk   = (idx >> 9) & 3;
    int n    = (idx >> 11) & 1;
    int wc   = (idx >> 12) & 1;
    int rest = idx >> 13;
    int ch   = rest % CHN;
    int br   = rest / CHN;
    int col  = ch * 64 + wc * 32 + n * 16 + (lane & 15);
    int k    = kk * 32 + (lane >> 4) * 8 + e;
    const float* W = (br == 0) ? W0 : ((br == 1) ? W1 : W2);
    float v = (col < M) ? W[(size_t)k * M + col] : 0.f;
    _Float16 h = (_Float16)v;
    dst[idx] = h;
    dst[total + idx] = (_Float16)(v - (float)h);
}

// ---------------- split-f16 MFMA GEMM: X in swizzled LDS, W fragment-coalesced from L2 ----
template<int CHN>
__global__ __launch_bounds__(256)
void gemm3(const float* __restrict__ X, const _Float16* __restrict__ Wf,
           const float* __restrict__ b0, const float* __restrict__ b1,
           const float* __restrict__ b2,
           float* __restrict__ out0, _Float16* __restrict__ out1, _Float16* __restrict__ out2,
           int M, int nrows)
{
    __shared__ _Float16 xh[64 * 128], xl[64 * 128];   // 32 KB total

    const int tid  = threadIdx.x;
    const int row0 = blockIdx.x * 64;
    const int ch   = blockIdx.y;
    const int plane = 3 * CHN * 2 * 2 * 4 * 512;

    float4 xr[8];
    #pragma unroll
    for (int i = 0; i < 8; ++i) {
        int idx = tid + i * 256;
        int row = idx >> 5;
        int k   = (idx & 31) * 4;
        int gr  = row0 + row;
        xr[i] = (gr < nrows) ? *(const float4*)(X + (size_t)gr * 128 + k)
                             : make_float4(0.f, 0.f, 0.f, 0.f);
    }
    #pragma unroll
    for (int i = 0; i < 8; ++i) {
        int idx = tid + i * 256;
        int row = idx >> 5;
        int k   = (idx & 31) * 4;
        float vv[4] = {xr[i].x, xr[i].y, xr[i].z, xr[i].w};
        f16x4 h, l;
        #pragma unroll
        for (int j = 0; j < 4; ++j) {
            _Float16 hj = (_Float16)vv[j];
            h[j] = hj;
            l[j] = (_Float16)(vv[j] - (float)hj);
        }
        int o = swz(row, k);
        *(f16x4*)&xh[o] = h;
        *(f16x4*)&xl[o] = l;
    }
    __syncthreads();

    const int lane = tid & 63;
    const int wid  = tid >> 6;
    const int wr   = wid >> 1, wc = wid & 1;
    const int r    = lane & 15, g = lane >> 4;

    f16x8 Ah[2][4], Al[2][4];
    #pragma unroll
    for (int m = 0; m < 2; ++m)
        #pragma unroll
        for (int kk = 0; kk < 4; ++kk) {
            int o = swz(wr * 32 + m * 16 + r, kk * 32 + g * 8);
            Ah[m][kk] = *(const f16x8*)&xh[o];
            Al[m][kk] = *(const f16x8*)&xl[o];
        }

    #pragma unroll
    for (int br = 0; br < 3; ++br) {
        f32x4 acc[2][2];
        #pragma unroll
        for (int m = 0; m < 2; ++m)
            #pragma unroll
            for (int n = 0; n < 2; ++n)
                acc[m][n] = (f32x4){0.f, 0.f, 0.f, 0.f};

        #pragma unroll
        for (int n = 0; n < 2; ++n) {
            size_t fb = ((((size_t)(br * CHN + ch) * 2 + wc) * 2 + n) * 4) * 512 + lane * 8;
            f16x8 Bh[4], Bl[4];
            #pragma unroll
            for (int kk = 0; kk < 4; ++kk) {
                Bh[kk] = *(const f16x8*)&Wf[fb + kk * 512];
                Bl[kk] = *(const f16x8*)&Wf[plane + fb + kk * 512];
            }
            #pragma unroll
            for (int kk = 0; kk < 4; ++kk) {
                #pragma unroll
                for (int m = 0; m < 2; ++m) {
                    acc[m][n] = __builtin_amdgcn_mfma_f32_16x16x32_f16(Ah[m][kk], Bh[kk], acc[m][n], 0, 0, 0);
                    acc[m][n] = __builtin_amdgcn_mfma_f32_16x16x32_f16(Ah[m][kk], Bl[kk], acc[m][n], 0, 0, 0);
                    acc[m][n] = __builtin_amdgcn_mfma_f32_16x16x32_f16(Al[m][kk], Bh[kk], acc[m][n], 0, 0, 0);
                }
            }
        }

        #pragma unroll
        for (int m = 0; m < 2; ++m)
            #pragma unroll
            for (int n = 0; n < 2; ++n) {
                int col = ch * 64 + wc * 32 + n * 16 + r;
                if (col >= M) continue;
                if (br == 0) {
                    float bs = b0[col] + b1[col] + b2[col];
                    #pragma unroll
                    for (int i = 0; i < 4; ++i) {
                        int row = row0 + wr * 32 + m * 16 + g * 4 + i;
                        if (row < nrows)
                            out0[(size_t)row * M + col] = acc[m][n][i] + bs;
                    }
                } else {
                    _Float16* outp = (br == 1) ? out1 : out2;
                    #pragma unroll
                    for (int i = 0; i < 4; ++i) {
                        int row = row0 + wr * 32 + m * 16 + g * 4 + i;
                        if (row < nrows)
                            outp[(size_t)row * M + col] = (_Float16)acc[m][n][i];
                    }
                }
            }
    }
}

// ---------------- combined CSR build over both edge sets (2E edges) ----------------
__global__ void zero_i32(int* __restrict__ p, int n)
{
    int i = blockIdx.x * 256 + threadIdx.x;
    if (i < n) p[i] = 0;
}

__global__ void hist_c(const int* __restrict__ ei1, const int* __restrict__ ei2,
                       int E, int* __restrict__ cnt)
{
    int i = blockIdx.x * 256 + threadIdx.x;
    if (i >= 2 * E) return;
    int d = (i < E) ? ei1[E + i] : ei2[E + (i - E)];
    atomicAdd(&cnt[d], 1);
}

__global__ void scan_phase1(const int* __restrict__ cnt, int ncnt, int* __restrict__ bsums, int n)
{
    __shared__ int s[256];
    int tid = threadIdx.x;
    int i = blockIdx.x * 256 + tid;
    int v = (i < n && i < ncnt) ? cnt[i] : 0;
    s[tid] = v; __syncthreads();
    for (int off = 128; off; off >>= 1) {
        if (tid < off) s[tid] += s[tid + off];
        __syncthreads();
    }
    if (tid == 0) bsums[blockIdx.x] = s[0];
}

__global__ void scan_phase2(int* __restrict__ bsums, int nb)
{
    __shared__ int s[256];
    int tid = threadIdx.x;
    int v = (tid < nb) ? bsums[tid] : 0;
    s[tid] = v; __syncthreads();
    for (int off = 1; off < 256; off <<= 1) {
        int t = (tid >= off) ? s[tid - off] : 0;
        __syncthreads();
        s[tid] += t;
        __syncthreads();
    }
    if (tid < nb) bsums[tid] = s[tid] - v;   // exclusive
}

// also zeroes cnt (reused as fill cursor in binplace)
__global__ void scan_phase3(int* __restrict__ cnt, int ncnt,
                            const int* __restrict__ bsums, int* __restrict__ row_ptr, int n)
{
    __shared__ int s[256];
    int tid = threadIdx.x;
    int i = blockIdx.x * 256 + tid;
    int v = (i < n && i < ncnt) ? cnt[i] : 0;
    s[tid] = v; __syncthreads();
    for (int off = 1; off < 256; off <<= 1) {
        int t = (tid >= off) ? s[tid - off] : 0;
        __syncthreads();
        s[tid] += t;
        __syncthreads();
    }
    if (i < n) {
        row_ptr[i] = s[tid] - v + bsums[blockIdx.x];
        if (i < ncnt) cnt[i] = 0;
    }
}

__global__ void init_bincur(const int* __restrict__ rp, int N, int nbins, int* __restrict__ bincur)
{
    int b = blockIdx.x * 256 + threadIdx.x;
    if (b < nbins) {
        int r = b << 9;
        bincur[b] = rp[r < N ? r : N];
    }
}

// ---------------- phase C: bin-bucketed staging of edge records ----------------
constexpr int EPB  = 2048;
constexpr int MAXB = 128;

__global__ __launch_bounds__(256)
void binfill(const int* __restrict__ ei1, const float* __restrict__ ew1,
             const int* __restrict__ ei2, const float* __restrict__ ew2,
             int E, int N, int nbins, int* __restrict__ bincur,
             long long* __restrict__ stage, unsigned short* __restrict__ soff)
{
    __shared__ int hist[MAXB];
    __shared__ int scanb[MAXB];
    __shared__ int gbase[MAXB];
    __shared__ long long srec[EPB];
    __shared__ unsigned short sdo[EPB];
    __shared__ unsigned char  sbin[EPB];

    const int t = threadIdx.x;
    const long long base = (long long)blockIdx.x * EPB;
    int total = 2 * E - (int)base; if (total > EPB) total = EPB;

    for (int i = t; i < MAXB; i += 256) hist[i] = 0;
    __syncthreads();

    int myb[8], myr[8], myo[8];
    long long myrec[8];
    #pragma unroll
    for (int k = 0; k < 8; ++k) {
        int i = t + k * 256;
        myb[k] = -1;
        if (i < total) {
            int j = (int)(base + i);
            int set = (j >= E);
            int e = set ? j - E : j;
            const int* ei = set ? ei2 : ei1;
            int d = ei[E + e];
            int s = ei[e] + (set ? N : 0);
            float w = set ? ew2[e] : ew1[e];
            myb[k] = d >> 9;
            myo[k] = d & 511;
            myrec[k] = ((long long)__float_as_int(w) << 32) | (unsigned)s;
            myr[k] = atomicAdd(&hist[myb[k]], 1);
        }
    }
    __syncthreads();

    if (t < MAXB) scanb[t] = hist[t];
    __syncthreads();
    for (int off = 1; off < MAXB; off <<= 1) {
        int tv = 0;
        if (t < MAXB && t >= off) tv = scanb[t - off];
        __syncthreads();
        if (t < MAXB) scanb[t] += tv;
        __syncthreads();
    }
    if (t < nbins && hist[t] > 0)
        gbase[t] = atomicAdd(&bincur[t], hist[t]);
    __syncthreads();

    #pragma unroll
    for (int k = 0; k < 8; ++k) {
        if (myb[k] >= 0) {
            int slot = scanb[myb[k]] - hist[myb[k]] + myr[k];
            srec[slot] = myrec[k];
            sdo[slot]  = (unsigned short)myo[k];
            sbin[slot] = (unsigned char)myb[k];
        }
    }
    __syncthreads();

    #pragma unroll
    for (int k = 0; k < 8; ++k) {
        int i = t + k * 256;
        if (i < total) {
            int b = sbin[i];
            int addr = gbase[b] + (i - (scanb[b] - hist[b]));
            stage[addr] = srec[i];
            soff[addr]  = sdo[i];
        }
    }
}

// ---------------- phase D: within-bin scatter to final CSR slots (L2-local) ----------------
__global__ __launch_bounds__(256)
void binplace(const long long* __restrict__ stage, const unsigned short* __restrict__ soff,
              const int* __restrict__ rp, int N, int* __restrict__ cur,
              long long* __restrict__ pack)
{
    int bin  = blockIdx.x >> 1;
    int half = blockIdx.x & 1;
    int r0 = bin << 9;
    int r1 = r0 + 512; if (r1 > N) r1 = N;
    if (r0 >= N) return;
    int beg = rp[r0], end = rp[r1];
    int mid = beg + ((end - beg + 1) >> 1);
    int lo = half ? mid : beg;
    int hi = half ? end : mid;
    for (int i = lo + threadIdx.x; i < hi; i += 256) {
        long long rec = stage[i];
        int d = r0 + soff[i];
        int p = rp[d] + atomicAdd(&cur[d], 1);
        pack[p] = rec;
    }
}

// ---------------- gather (width 128), 16 lanes/row, f16x8, 4-deep MLP ----------------
__global__ __launch_bounds__(256)
void gather_c128(const _Float16* __restrict__ hc, const int* __restrict__ rp,
                 const long long* __restrict__ pack, float* __restrict__ out, int N)
{
    int row = blockIdx.x * 16 + (threadIdx.x >> 4);
    if (row >= N) return;
    int lane = threadIdx.x & 15;
    int beg = rp[row], end = rp[row + 1];
    // hoist the independent out-row read: its latency hides under the gather chain
    float* o = out + (size_t)row * 128 + lane * 8;
    float4 c0 = *(const float4*)o;
    float4 c1 = *(const float4*)(o + 4);
    float a[8] = {};
    int i = beg;
    for (; i + 4 <= end; i += 4) {
        long long q0 = __builtin_nontemporal_load(&pack[i]);
        long long q1 = __builtin_nontemporal_load(&pack[i + 1]);
        long long q2 = __builtin_nontemporal_load(&pack[i + 2]);
        long long q3 = __builtin_nontemporal_load(&pack[i + 3]);
        f16x8 v0 = *(const f16x8*)(hc + (size_t)(unsigned)q0 * 128 + lane * 8);
        f16x8 v1 = *(const f16x8*)(hc + (size_t)(unsigned)q1 * 128 + lane * 8);
        f16x8 v2 = *(const f16x8*)(hc + (size_t)(unsigned)q2 * 128 + lane * 8);
        f16x8 v3 = *(const f16x8*)(hc + (size_t)(unsigned)q3 * 128 + lane * 8);
        float w0 = __int_as_float((int)(q0 >> 32));
        float w1 = __int_as_float((int)(q1 >> 32));
        float w2 = __int_as_float((int)(q2 >> 32));
        float w3 = __int_as_float((int)(q3 >> 32));
        #pragma unroll
        for (int j = 0; j < 8; ++j) {
            a[j] = fmaf(w0, (float)v0[j], a[j]);
            a[j] = fmaf(w1, (float)v1[j], a[j]);
            a[j] = fmaf(w2, (float)v2[j], a[j]);
            a[j] = fmaf(w3, (float)v3[j], a[j]);
        }
    }
    for (; i < end; ++i) {
        long long q0 = __builtin_nontemporal_load(&pack[i]);
        f16x8 v0 = *(const f16x8*)(hc + (size_t)(unsigned)q0 * 128 + lane * 8);
        float w0 = __int_as_float((int)(q0 >> 32));
        #pragma unroll
        for (int j = 0; j < 8; ++j) a[j] = fmaf(w0, (float)v0[j], a[j]);
    }
    c0.x += a[0]; c0.y += a[1]; c0.z += a[2]; c0.w += a[3];
    c1.x += a[4]; c1.y += a[5]; c1.z += a[6]; c1.w += a[7];
    *(float4*)o = c0;
    *(float4*)(o + 4) = c1;
}

// ---------------- final: gather (width 40) + log_softmax fused ----------------
__global__ __launch_bounds__(256)
void gather_ls40(const _Float16* __restrict__ hc, const int* __restrict__ rp,
                 const long long* __restrict__ pack, const float* __restrict__ xlin,
                 float* __restrict__ out, int N)
{
    int row = blockIdx.x * 16 + (threadIdx.x >> 4);
    int lane = threadIdx.x & 15;
    if (row >= N) return;
    bool act = (lane < 10);

    float v0 = -INFINITY, v1 = -INFINITY, v2 = -INFINITY, v3 = -INFINITY;
    if (act) {
        float a0 = 0.f, a1 = 0.f, a2 = 0.f, a3 = 0.f;
        int beg = rp[row], end = rp[row + 1];
        int i = beg;
        for (; i + 4 <= end; i += 4) {
            long long q0 = __builtin_nontemporal_load(&pack[i]);
            long long q1 = __builtin_nontemporal_load(&pack[i + 1]);
            long long q2 = __builtin_nontemporal_load(&pack[i + 2]);
            long long q3 = __builtin_nontemporal_load(&pack[i + 3]);
            f16x4 va = *(const f16x4*)(hc + (size_t)(unsigned)q0 * 40 + lane * 4);
            f16x4 vb = *(const f16x4*)(hc + (size_t)(unsigned)q1 * 40 + lane * 4);
            f16x4 vc = *(const f16x4*)(hc + (size_t)(unsigned)q2 * 40 + lane * 4);
            f16x4 vd = *(const f16x4*)(hc + (size_t)(unsigned)q3 * 40 + lane * 4);
            float wa = __int_as_float((int)(q0 >> 32));
            float wb = __int_as_float((int)(q1 >> 32));
            float wc = __int_as_float((int)(q2 >> 32));
            float wd = __int_as_float((int)(q3 >> 32));
            a0 = fmaf(wa, (float)va[0], a0); a1 = fmaf(wa, (float)va[1], a1);
            a2 = fmaf(wa, (float)va[2], a2); a3 = fmaf(wa, (float)va[3], a3);
            a0 = fmaf(wb, (float)vb[0], a0); a1 = fmaf(wb, (float)vb[1], a1);
            a2 = fmaf(wb, (float)vb[2], a2); a3 = fmaf(wb, (float)vb[3], a3);
            a0 = fmaf(wc, (float)vc[0], a0); a1 = fmaf(wc, (float)vc[1], a1);
            a2 = fmaf(wc, (float)vc[2], a2); a3 = fmaf(wc, (float)vc[3], a3);
            a0 = fmaf(wd, (float)vd[0], a0); a1 = fmaf(wd, (float)vd[1], a1);
            a2 = fmaf(wd, (float)vd[2], a2); a3 = fmaf(wd, (float)vd[3], a3);
        }
        for (; i < end; ++i) {
            long long q0 = __builtin_nontemporal_load(&pack[i]);
            f16x4 va = *(const f16x4*)(hc + (size_t)(unsigned)q0 * 40 + lane * 4);
            float wa = __int_as_float((int)(q0 >> 32));
            a0 = fmaf(wa, (float)va[0], a0); a1 = fmaf(wa, (float)va[1], a1);
            a2 = fmaf(wa, (float)va[2], a2); a3 = fmaf(wa, (float)va[3], a3);
        }
        float4 c = *(const float4*)(xlin + (size_t)row * 40 + lane * 4);
        v0 = c.x + a0; v1 = c.y + a1; v2 = c.z + a2; v3 = c.w + a3;
    }

    float m = fmaxf(fmaxf(v0, v1), fmaxf(v2, v3));
    #pragma unroll
    for (int off = 8; off; off >>= 1) m = fmaxf(m, __shfl_xor(m, off, 16));
    float s = 0.f;
    if (act) s = expf(v0 - m) + expf(v1 - m) + expf(v2 - m) + expf(v3 - m);
    #pragma unroll
    for (int off = 8; off; off >>= 1) s += __shfl_xor(s, off, 16);
    float ls = m + logf(s);

    if (act) {
        float* o = out + (size_t)row * 40 + lane * 4;
        o[0] = v0 - ls; o[1] = v1 - ls; o[2] = v2 - ls; o[3] = v3 - ls;
    }
}

// ---------------- launch ----------------
extern "C" void kernel_launch(void* const* d_in, const int* in_sizes, int n_in,
                              void* d_out, int out_size, void* d_ws, size_t ws_size,
                              hipStream_t stream)
{
    const float* x    = (const float*)d_in[0];
    const int*   ei1  = (const int*)  d_in[1];
    const float* ew1  = (const float*)d_in[2];
    const int*   ei2  = (const int*)  d_in[3];
    const float* ew2  = (const float*)d_in[4];

    const float* W_ln1 = (const float*)d_in[5];   const float* b_ln1 = (const float*)d_in[6];
    const float* W_c11 = (const float*)d_in[7];   const float* b_c11 = (const float*)d_in[8];
    const float* W_c21 = (const float*)d_in[9];   const float* b_c21 = (const float*)d_in[10];
    const float* W_ln2 = (const float*)d_in[11];  const float* b_ln2 = (const float*)d_in[12];
    const float* W_c12 = (const float*)d_in[13];  const float* b_c12 = (const float*)d_in[14];
    const float* W_c22 = (const float*)d_in[15];  const float* b_c22 = (const float*)d_in[16];
    const float* W_ln3 = (const float*)d_in[17];  const float* b_ln3 = (const float*)d_in[18];
    const float* W_c13 = (const float*)d_in[19];  const float* b_c13 = (const float*)d_in[20];
    const float* W_c23 = (const float*)d_in[21];  const float* b_c23 = (const float*)d_in[22];

    const int N = in_sizes[0] / 128;   // 50000
    const int E = in_sizes[2];         // 600000
    const int nbins = (N + 511) >> 9;  // 98

    // ---- workspace layout ----
    auto align_up = [](size_t v) { return (v + 255) & ~(size_t)255; };
    char* base = (char*)d_ws;
    size_t off = 0;
    auto take = [&](size_t bytes) { char* p = base + off; off += align_up(bytes); return p; };

    float*     xA   = (float*)    take((size_t)N * 128 * 4);
    float*     xB   = (float*)    take((size_t)N * 128 * 4);
    _Float16*  hc   = (_Float16*) take((size_t)2 * N * 128 * 2);

    _Float16* Wt1 = (_Float16*)take((size_t)2 * 49152 * 2);
    _Float16* Wt2 = (_Float16*)take((size_t)2 * 49152 * 2);
    _Float16* Wt3 = (_Float16*)take((size_t)2 * 24576 * 2);

    int*       cnt  = (int*)      take((size_t)N * 4);
    int*       rp   = (int*)      take((size_t)(N + 1) * 4);
    long long* pack = (long long*)take((size_t)2 * E * 8);
    int*       bs   = (int*)      take(256 * 4);
    int*       bincur = (int*)    take(MAXB * 4);

    long long*      stage = (long long*)hc;
    unsigned short* soff  = (unsigned short*)((char*)hc + (size_t)2 * E * 8);

    dim3 blk(256);
    const int gN   = (N + 255) / 256;
    const int gN1  = (N + 1 + 255) / 256;
    const int gE2  = (2 * E + 255) / 256;
    const int gBF  = (2 * E + EPB - 1) / EPB;
    const int gRT  = (N + 63) / 64;
    dim3 gg3_128(gRT, 2);
    dim3 gg3_40(gRT, 1);
    dim3 gg16((N + 15) / 16);

    // ---- W preprocessing (fragment-major) ----
    wsplit3<<<(49152 + 255) / 256, blk, 0, stream>>>(W_ln1, W_c11, W_c21, Wt1, 128, 2);
    wsplit3<<<(49152 + 255) / 256, blk, 0, stream>>>(W_ln2, W_c12, W_c22, Wt2, 128, 2);
    wsplit3<<<(24576 + 255) / 256, blk, 0, stream>>>(W_ln3, W_c13, W_c23, Wt3, 40, 1);

    // ---- build combined CSR ----
    zero_i32<<<gN, blk, 0, stream>>>(cnt, N);
    hist_c<<<gE2, blk, 0, stream>>>(ei1, ei2, E, cnt);
    scan_phase1<<<gN1, blk, 0, stream>>>(cnt, N, bs, N + 1);
    scan_phase2<<<1, blk, 0, stream>>>(bs, gN1);
    scan_phase3<<<gN1, blk, 0, stream>>>(cnt, N, bs, rp, N + 1);
    init_bincur<<<1, blk, 0, stream>>>(rp, N, nbins, bincur);
    binfill<<<gBF, blk, 0, stream>>>(ei1, ew1, ei2, ew2, E, N, nbins, bincur, stage, soff);
    binplace<<<nbins * 2, blk, 0, stream>>>(stage, soff, rp, N, cnt, pack);

    // ---- Block 1: x -> xA ----
    gemm3<2><<<gg3_128, blk, 0, stream>>>(x, Wt1, b_ln1, b_c11, b_c21, xA, hc, hc + (size_t)N * 128, 128, N);
    gather_c128<<<gg16, blk, 0, stream>>>(hc, rp, pack, xA, N);

    // ---- Block 2: xA -> xB ----
    gemm3<2><<<gg3_128, blk, 0, stream>>>(xA, Wt2, b_ln2, b_c12, b_c22, xB, hc, hc + (size_t)N * 128, 128, N);
    gather_c128<<<gg16, blk, 0, stream>>>(hc, rp, pack, xB, N);

    // ---- Block 3: xB -> xA (width 40), then fused gather+log_softmax -> d_out ----
    gemm3<1><<<gg3_40, blk, 0, stream>>>(xB, Wt3, b_ln3, b_c13, b_c23, xA, hc, hc + (size_t)N * 40, 40, N);
    gather_ls40<<<gg16, blk, 0, stream>>>(hc, rp, pack, xA, (float*)d_out, N);
}